// Round 9
// baseline (139.404 us; speedup 1.0000x reference)
//
#include <hip/hip_runtime.h>

// dims from the reference
#define BB 2
#define PP 512
#define NN 8
#define HH 32

typedef float f4     __attribute__((ext_vector_type(4)));
typedef float f32x4  __attribute__((ext_vector_type(4)));
typedef short bf16x8 __attribute__((ext_vector_type(8)));

// float -> bf16 bits, round-nearest-even
__device__ __forceinline__ short f2bf(float f) {
  union { float f; unsigned u; } v; v.f = f;
  unsigned r = v.u + 0x7FFFu + ((v.u >> 16) & 1u);
  return (short)(r >> 16);
}

// ---------------------------------------------------------------------------
// Kernel 1: prep_all
//  blocks 0..511  : tmpT[b,p1,n,h3,h2] = bf16( sum_h1 d * W ), W read direct.
//  blocks 512..639: eBf tiled bf16 fragment layout (1KB dense B-frag loads).
// ---------------------------------------------------------------------------
__global__ __launch_bounds__(256) void prep_all_kernel(
    const float* __restrict__ d, const float* __restrict__ W,
    const float* __restrict__ e, short* __restrict__ tmpT,
    short* __restrict__ eBf) {
  const int bid = blockIdx.x;
  const int t   = threadIdx.x;

  if (bid >= 512) {                    // ---- eBf tiled conversion ----
    const int ft = (bid - 512) * 256 + t;      // 0..32767
    const int l  = ft & 63;
    const int n  = (ft >> 6) & 7;
    const int pt = (ft >> 9) & 31;
    const int b  = ft >> 14;
    const float* src =
        e + (((size_t)(b * PP + pt * 16 + (l & 15)) * NN + n) * HH + (l >> 4) * 8);
    const f4 e0 = *(const f4*)src;
    const f4 e1 = *(const f4*)(src + 4);
    bf16x8 v;
    v[0] = f2bf(e0[0]); v[1] = f2bf(e0[1]); v[2] = f2bf(e0[2]); v[3] = f2bf(e0[3]);
    v[4] = f2bf(e1[0]); v[5] = f2bf(e1[1]); v[6] = f2bf(e1[2]); v[7] = f2bf(e1[3]);
    *(bf16x8*)(eBf + (size_t)ft * 8) = v;
    return;
  }

  // ---- prep part: block = (b, n-pair, 8 p1) ----
  const int b      = bid >> 8;
  const int rem    = bid & 255;
  const int npair  = rem >> 6;         // 0..3
  const int p1base = (rem & 63) * 8;

  __shared__ float dsh[2][32][8];      // [n'][h1][p1l]
  {
    const int h1 = t & 31, p1l = (t >> 5) & 7;
    #pragma unroll
    for (int r = 0; r < 2; ++r)
      dsh[r][h1][p1l] =
          d[(size_t)((b * PP + p1base + p1l) * NN + npair * 2 + r) * HH + h1];
  }
  __syncthreads();

  const int np  = t >> 7;              // 0/1
  const int h3  = (t >> 2) & 31;
  const int h2g = t & 3;               // h2 base = h2g*8
  const int n   = npair * 2 + np;

  float acc[8][8];                     // [p1l][h2loc]
  #pragma unroll
  for (int p = 0; p < 8; ++p)
    #pragma unroll
    for (int q = 0; q < 8; ++q) acc[p][q] = 0.f;

  const float* wb = W + (size_t)n * 32768 + h2g * 8 * 32 + h3;
  for (int h1 = 0; h1 < 32; ++h1) {
    const float* wr = wb + (size_t)h1 * 1024;
    float wq[8];
    #pragma unroll
    for (int q = 0; q < 8; ++q) wq[q] = wr[q * 32];
    const f4 d0 = *(const f4*)&dsh[np][h1][0];
    const f4 d1 = *(const f4*)&dsh[np][h1][4];
    #pragma unroll
    for (int p = 0; p < 4; ++p) {
      #pragma unroll
      for (int q = 0; q < 4; ++q) {
        acc[p][q]         = fmaf(d0[p], wq[q],     acc[p][q]);
        acc[p][q + 4]     = fmaf(d0[p], wq[q + 4], acc[p][q + 4]);
        acc[p + 4][q]     = fmaf(d1[p], wq[q],     acc[p + 4][q]);
        acc[p + 4][q + 4] = fmaf(d1[p], wq[q + 4], acc[p + 4][q + 4]);
      }
    }
  }

  const size_t obase =
      ((size_t)(b * PP + p1base) * NN + n) * (HH * HH) + h3 * 32 + h2g * 8;
  #pragma unroll
  for (int p = 0; p < 8; ++p) {
    bf16x8 v;
    #pragma unroll
    for (int q = 0; q < 8; ++q) v[q] = f2bf(acc[p][q]);
    *(bf16x8*)(tmpT + obase + (size_t)p * (NN * HH * HH)) = v;
  }
}

// ---------------------------------------------------------------------------
// Kernel 2: vmain v9 — R8 structure + write-stream locality:
//   (a) bijective XCD swizzle: swz = (bid&7)*128 + (bid>>3) -> each XCD owns
//       a CONTIGUOUS 64MB output chunk (default round-robin scatters it).
//   (b) wave-cooperative write front: pt = i*4 + wv -> the block's 4 waves
//       write one contiguous 64KB window advancing monotonically.
//   Everything else identical to R8 (A-frags pinned, dense eBf B-loads,
//   XOR-swizzled LDS transpose, 512B-dense dwordx4 stores, 4 blocks/CU).
// ---------------------------------------------------------------------------
__global__ __launch_bounds__(256, 4) void vmain_kernel(
    const short* __restrict__ eBf, const short* __restrict__ tmpT,
    float* __restrict__ out) {
  const int bid = blockIdx.x;
  const int swz = ((bid & 7) << 7) + (bid >> 3);  // bijective XCD swizzle
  const int b   = swz >> 9;
  const int p1  = swz & 511;
  const int t   = threadIdx.x;
  const int wv  = t >> 6;
  const int l   = t & 63;
  const int lr  = l & 15;
  const int lk  = l >> 4;

  __shared__ float lbuf[4][16][128];   // 32 KB: per-wave transpose buffers
  float* wl = &lbuf[wv][0][0];

  // A-fragments: T^T rows h3 = c*16 + lr, k = h2 = 8*lk + j (contiguous 16B)
  bf16x8 bfr[8][2];
  const short* tb = tmpT + (size_t)(b * PP + p1) * (NN * HH * HH);
  #pragma unroll
  for (int n = 0; n < 8; ++n)
    #pragma unroll
    for (int c = 0; c < 2; ++c)
      bfr[n][c] = *(const bf16x8*)(tb + n * (HH * HH) + (c * 16 + lr) * 32 + lk * 8);

  const short* eb   = eBf + (size_t)b * (32 * NN * 512);
  float*       outb = out + (size_t)(b * PP + p1) * (PP * NN * HH);
  const f32x4  z    = {0.f, 0.f, 0.f, 0.f};

  for (int i = 0; i < 8; ++i) {
    const int pt = i * 4 + wv;         // sequential block-level write front
    const int m0 = pt * 16;
    #pragma unroll
    for (int half = 0; half < 2; ++half) {
      const int n0 = half * 4;
      #pragma unroll
      for (int nn = 0; nn < 4; ++nn) {
        const int n = n0 + nn;
        const bf16x8 a =
            *(const bf16x8*)(eb + (((size_t)(pt * NN + n)) << 9) + l * 8);
        const f32x4 c0 = __builtin_amdgcn_mfma_f32_16x16x32_bf16(bfr[n][0], a, z, 0, 0, 0);
        const f32x4 c1 = __builtin_amdgcn_mfma_f32_16x16x32_bf16(bfr[n][1], a, z, 0, 0, 0);
        const int s0 = (nn * 8 + lk)     ^ (lr & 7);
        const int s1 = (nn * 8 + 4 + lk) ^ (lr & 7);
        *(f32x4*)(wl + lr * 128 + s0 * 4) = c0;
        *(f32x4*)(wl + lr * 128 + s1 * 4) = c1;
      }
      #pragma unroll
      for (int j = 0; j < 8; ++j) {
        const int row  = 2 * j + (l >> 5);
        const int slot = l & 31;
        const f32x4 v = *(const f32x4*)(wl + row * 128 + ((slot ^ (row & 7)) * 4));
        *(f32x4*)(outb + (size_t)(m0 + row) * (NN * HH) + n0 * HH + slot * 4) = v;
      }
    }
  }
}

// ---------------------------------------------------------------------------
// Fallback (no/small ws): self-contained fused kernel (correct, slower).
// ---------------------------------------------------------------------------
__global__ __launch_bounds__(256, 4) void fused_kernel(
    const float* __restrict__ d, const float* __restrict__ e,
    const float* __restrict__ W, float* __restrict__ out) {
  const int bid = blockIdx.x;
  const int b   = bid >> 9;
  const int p1  = bid & 511;
  const int t   = threadIdx.x;

  __shared__ float dsh[NN * HH];
  __shared__ short tsh[NN * HH * HH];
  dsh[t] = d[(size_t)(b * PP + p1) * (NN * HH) + t];
  __syncthreads();

  const int h3  = t & 31;
  const int h2b = t >> 5;
  for (int n = 0; n < 8; ++n) {
    f4 dv[8];
    #pragma unroll
    for (int j = 0; j < 8; ++j) dv[j] = *(const f4*)&dsh[n * 32 + j * 4];
    const float* Wn = W + (size_t)n * (HH * HH * HH);
    #pragma unroll
    for (int h2s = 0; h2s < 4; ++h2s) {
      const int h2 = h2s * 8 + h2b;
      float acc = 0.f;
      #pragma unroll
      for (int j = 0; j < 8; ++j)
        #pragma unroll
        for (int k = 0; k < 4; ++k)
          acc = fmaf(dv[j][k], Wn[(j * 4 + k) * 1024 + h2 * 32 + h3], acc);
      tsh[n * 1024 + h3 * 32 + h2] = f2bf(acc);
    }
  }
  __syncthreads();

  const int wv = t >> 6;
  const int l  = t & 63;
  const int lr = l & 15;
  const int lk = l >> 4;
  bf16x8 bfr[8][2];
  #pragma unroll
  for (int n = 0; n < 8; ++n)
    #pragma unroll
    for (int c = 0; c < 2; ++c)
      bfr[n][c] = *(const bf16x8*)&tsh[n * (HH * HH) + (c * 16 + lr) * 32 + lk * 8];

  const float* eb   = e + (size_t)b * (PP * NN * HH);
  float*       outb = out + (size_t)(b * PP + p1) * (PP * NN * HH);
  const f32x4  z    = {0.f, 0.f, 0.f, 0.f};
  for (int i = 0; i < 8; ++i) {
    const int m0 = (wv * 8 + i) * 16;
    #pragma unroll
    for (int n = 0; n < 8; ++n) {
      const float* ep = eb + (size_t)(((m0 + lr) * NN + n) * HH + lk * 8);
      const f4 e0 = *(const f4*)ep;
      const f4 e1 = *(const f4*)(ep + 4);
      bf16x8 a;
      a[0] = f2bf(e0[0]); a[1] = f2bf(e0[1]); a[2] = f2bf(e0[2]); a[3] = f2bf(e0[3]);
      a[4] = f2bf(e1[0]); a[5] = f2bf(e1[1]); a[6] = f2bf(e1[2]); a[7] = f2bf(e1[3]);
      const f32x4 c0 = __builtin_amdgcn_mfma_f32_16x16x32_bf16(bfr[n][0], a, z, 0, 0, 0);
      const f32x4 c1 = __builtin_amdgcn_mfma_f32_16x16x32_bf16(bfr[n][1], a, z, 0, 0, 0);
      float* op = outb + (size_t)(m0 + lr) * (NN * HH) + n * HH + lk * 4;
      *(f32x4*)op        = c0;
      *(f32x4*)(op + 16) = c1;
    }
  }
}

extern "C" void kernel_launch(void* const* d_in, const int* in_sizes, int n_in,
                              void* d_out, int out_size, void* d_ws, size_t ws_size,
                              hipStream_t stream) {
  const float* d = (const float*)d_in[0];
  const float* e = (const float*)d_in[1];
  const float* W = (const float*)d_in[2];
  float* out = (float*)d_out;

  const size_t tmp_bytes = (size_t)BB * PP * NN * HH * HH * sizeof(short); // 16.78 MB
  const size_t eb_bytes  = (size_t)BB * PP * NN * HH * sizeof(short);      // 512 KB
  if (ws_size >= tmp_bytes + eb_bytes) {
    short* tmpT = (short*)d_ws;
    short* eBf  = (short*)((char*)d_ws + tmp_bytes);
    prep_all_kernel<<<dim3(512 + 128), dim3(256), 0, stream>>>(d, W, e, tmpT, eBf);
    vmain_kernel<<<dim3(BB * PP), dim3(256), 0, stream>>>(eBf, tmpT, out);
  } else {
    fused_kernel<<<dim3(BB * PP), dim3(256), 0, stream>>>(d, e, W, out);
  }
}

// Round 10
// 126.927 us; speedup vs baseline: 1.0983x; 1.0983x over previous
//
#include <hip/hip_runtime.h>

// dims from the reference
#define BB 2
#define PP 512
#define NN 8
#define HH 32

typedef float f4     __attribute__((ext_vector_type(4)));
typedef float f32x4  __attribute__((ext_vector_type(4)));
typedef short bf16x8 __attribute__((ext_vector_type(8)));

// float -> bf16 bits, round-nearest-even
__device__ __forceinline__ short f2bf(float f) {
  union { float f; unsigned u; } v; v.f = f;
  unsigned r = v.u + 0x7FFFu + ((v.u >> 16) & 1u);
  return (short)(r >> 16);
}

// ---------------------------------------------------------------------------
// Kernel 1: prep_all (unchanged from R8)
//  blocks 0..511  : tmpT[b,p1,n,h3,h2] = bf16( sum_h1 d * W ), W read direct.
//  blocks 512..639: eBf tiled bf16 fragment layout (1KB dense B-frag loads).
// ---------------------------------------------------------------------------
__global__ __launch_bounds__(256) void prep_all_kernel(
    const float* __restrict__ d, const float* __restrict__ W,
    const float* __restrict__ e, short* __restrict__ tmpT,
    short* __restrict__ eBf) {
  const int bid = blockIdx.x;
  const int t   = threadIdx.x;

  if (bid >= 512) {                    // ---- eBf tiled conversion ----
    const int ft = (bid - 512) * 256 + t;      // 0..32767
    const int l  = ft & 63;
    const int n  = (ft >> 6) & 7;
    const int pt = (ft >> 9) & 31;
    const int b  = ft >> 14;
    const float* src =
        e + (((size_t)(b * PP + pt * 16 + (l & 15)) * NN + n) * HH + (l >> 4) * 8);
    const f4 e0 = *(const f4*)src;
    const f4 e1 = *(const f4*)(src + 4);
    bf16x8 v;
    v[0] = f2bf(e0[0]); v[1] = f2bf(e0[1]); v[2] = f2bf(e0[2]); v[3] = f2bf(e0[3]);
    v[4] = f2bf(e1[0]); v[5] = f2bf(e1[1]); v[6] = f2bf(e1[2]); v[7] = f2bf(e1[3]);
    *(bf16x8*)(eBf + (size_t)ft * 8) = v;
    return;
  }

  // ---- prep part: block = (b, n-pair, 8 p1) ----
  const int b      = bid >> 8;
  const int rem    = bid & 255;
  const int npair  = rem >> 6;         // 0..3
  const int p1base = (rem & 63) * 8;

  __shared__ float dsh[2][32][8];      // [n'][h1][p1l]
  {
    const int h1 = t & 31, p1l = (t >> 5) & 7;
    #pragma unroll
    for (int r = 0; r < 2; ++r)
      dsh[r][h1][p1l] =
          d[(size_t)((b * PP + p1base + p1l) * NN + npair * 2 + r) * HH + h1];
  }
  __syncthreads();

  const int np  = t >> 7;              // 0/1
  const int h3  = (t >> 2) & 31;
  const int h2g = t & 3;               // h2 base = h2g*8
  const int n   = npair * 2 + np;

  float acc[8][8];                     // [p1l][h2loc]
  #pragma unroll
  for (int p = 0; p < 8; ++p)
    #pragma unroll
    for (int q = 0; q < 8; ++q) acc[p][q] = 0.f;

  const float* wb = W + (size_t)n * 32768 + h2g * 8 * 32 + h3;
  for (int h1 = 0; h1 < 32; ++h1) {
    const float* wr = wb + (size_t)h1 * 1024;
    float wq[8];
    #pragma unroll
    for (int q = 0; q < 8; ++q) wq[q] = wr[q * 32];
    const f4 d0 = *(const f4*)&dsh[np][h1][0];
    const f4 d1 = *(const f4*)&dsh[np][h1][4];
    #pragma unroll
    for (int p = 0; p < 4; ++p) {
      #pragma unroll
      for (int q = 0; q < 4; ++q) {
        acc[p][q]         = fmaf(d0[p], wq[q],     acc[p][q]);
        acc[p][q + 4]     = fmaf(d0[p], wq[q + 4], acc[p][q + 4]);
        acc[p + 4][q]     = fmaf(d1[p], wq[q],     acc[p + 4][q]);
        acc[p + 4][q + 4] = fmaf(d1[p], wq[q + 4], acc[p + 4][q + 4]);
      }
    }
  }

  const size_t obase =
      ((size_t)(b * PP + p1base) * NN + n) * (HH * HH) + h3 * 32 + h2g * 8;
  #pragma unroll
  for (int p = 0; p < 8; ++p) {
    bf16x8 v;
    #pragma unroll
    for (int q = 0; q < 8; ++q) v[q] = f2bf(acc[p][q]);
    *(bf16x8*)(tmpT + obase + (size_t)p * (NN * HH * HH)) = v;
  }
}

// ---------------------------------------------------------------------------
// Kernel 2: vmain v10 — cooperative full-row epilogue.
//   All 4 waves work on the SAME 16-p2 tile: wave wv computes its 2 n-values
//   (64 cols) into shared [16][256] f32 (group-XOR swizzle, <=2-way),
//   one barrier, then each wave stores 4 COMPLETE rows: every store instr =
//   one fully-contiguous 1KB row (fill-like), tile window 16KB monotonic.
//   Double-buffered (32KB LDS), 1 barrier/tile, 4 blocks/CU, bfr 16 VGPRs.
// ---------------------------------------------------------------------------
__global__ __launch_bounds__(256, 4) void vmain_kernel(
    const short* __restrict__ eBf, const short* __restrict__ tmpT,
    float* __restrict__ out) {
  const int bid = blockIdx.x;
  const int b   = bid >> 9;
  const int p1  = bid & 511;
  const int t   = threadIdx.x;
  const int wv  = t >> 6;
  const int l   = t & 63;
  const int lr  = l & 15;
  const int lk  = l >> 4;
  const int n0w = wv * 2;              // this wave's n pair

  __shared__ float sh[2][16][256];     // 32 KB: double-buffered full-row tiles

  // A-fragments for this wave's two n: rows h3 = c*16+lr, k = h2 = 8*lk+j
  bf16x8 bfr[2][2];
  const short* tb = tmpT + (size_t)(b * PP + p1) * (NN * HH * HH);
  #pragma unroll
  for (int s = 0; s < 2; ++s)
    #pragma unroll
    for (int c = 0; c < 2; ++c)
      bfr[s][c] =
          *(const bf16x8*)(tb + (n0w + s) * 1024 + (c * 16 + lr) * 32 + lk * 8);

  const short* eb   = eBf + (size_t)b * (32 * NN * 512);
  float*       outb = out + (size_t)(b * PP + p1) * (PP * NN * HH);
  const f32x4  z    = {0.f, 0.f, 0.f, 0.f};

  for (int i = 0; i < 32; ++i) {       // pt = i, all waves cooperate
    const int bi = i & 1;
    // ---- compute this wave's 64 cols of the 16x256 tile ----
    #pragma unroll
    for (int s = 0; s < 2; ++s) {
      const int n = n0w + s;
      const bf16x8 a = *(const bf16x8*)(eb + (((size_t)(i * NN + n)) << 9) + l * 8);
      const f32x4 c0 = __builtin_amdgcn_mfma_f32_16x16x32_bf16(bfr[s][0], a, z, 0, 0, 0);
      const f32x4 c1 = __builtin_amdgcn_mfma_f32_16x16x32_bf16(bfr[s][1], a, z, 0, 0, 0);
      // lane holds p2-row = lr, h3 quads lk (c0) and 4+lk (c1) of col-block n
      const int g0 = (n * 8 + lk)     ^ (lr & 7);   // 16B-group swizzle
      const int g1 = (n * 8 + 4 + lk) ^ (lr & 7);
      *(f32x4*)(&sh[bi][lr][g0 * 4]) = c0;
      *(f32x4*)(&sh[bi][lr][g1 * 4]) = c1;
    }
    __syncthreads();                   // tile ready (dbl-buffer: 1 barrier/tile)
    // ---- store: 4 complete rows per wave, 1KB contiguous per instr ----
    #pragma unroll
    for (int k = 0; k < 4; ++k) {
      const int r = wv * 4 + k;
      const f32x4 v = *(const f32x4*)(&sh[bi][r][((l ^ (r & 7)) * 4)]);
      *(f32x4*)(outb + (size_t)(i * 16 + r) * 256 + l * 4) = v;
    }
  }
}

// ---------------------------------------------------------------------------
// Fallback (no/small ws): self-contained fused kernel (correct, slower).
// ---------------------------------------------------------------------------
__global__ __launch_bounds__(256, 4) void fused_kernel(
    const float* __restrict__ d, const float* __restrict__ e,
    const float* __restrict__ W, float* __restrict__ out) {
  const int bid = blockIdx.x;
  const int b   = bid >> 9;
  const int p1  = bid & 511;
  const int t   = threadIdx.x;

  __shared__ float dsh[NN * HH];
  __shared__ short tsh[NN * HH * HH];
  dsh[t] = d[(size_t)(b * PP + p1) * (NN * HH) + t];
  __syncthreads();

  const int h3  = t & 31;
  const int h2b = t >> 5;
  for (int n = 0; n < 8; ++n) {
    f4 dv[8];
    #pragma unroll
    for (int j = 0; j < 8; ++j) dv[j] = *(const f4*)&dsh[n * 32 + j * 4];
    const float* Wn = W + (size_t)n * (HH * HH * HH);
    #pragma unroll
    for (int h2s = 0; h2s < 4; ++h2s) {
      const int h2 = h2s * 8 + h2b;
      float acc = 0.f;
      #pragma unroll
      for (int j = 0; j < 8; ++j)
        #pragma unroll
        for (int k = 0; k < 4; ++k)
          acc = fmaf(dv[j][k], Wn[(j * 4 + k) * 1024 + h2 * 32 + h3], acc);
      tsh[n * 1024 + h3 * 32 + h2] = f2bf(acc);
    }
  }
  __syncthreads();

  const int wv = t >> 6;
  const int l  = t & 63;
  const int lr = l & 15;
  const int lk = l >> 4;
  bf16x8 bfr[8][2];
  #pragma unroll
  for (int n = 0; n < 8; ++n)
    #pragma unroll
    for (int c = 0; c < 2; ++c)
      bfr[n][c] = *(const bf16x8*)&tsh[n * (HH * HH) + (c * 16 + lr) * 32 + lk * 8];

  const float* eb   = e + (size_t)b * (PP * NN * HH);
  float*       outb = out + (size_t)(b * PP + p1) * (PP * NN * HH);
  const f32x4  z    = {0.f, 0.f, 0.f, 0.f};
  for (int i = 0; i < 8; ++i) {
    const int m0 = (wv * 8 + i) * 16;
    #pragma unroll
    for (int n = 0; n < 8; ++n) {
      const float* ep = eb + (size_t)(((m0 + lr) * NN + n) * HH + lk * 8);
      const f4 e0 = *(const f4*)ep;
      const f4 e1 = *(const f4*)(ep + 4);
      bf16x8 a;
      a[0] = f2bf(e0[0]); a[1] = f2bf(e0[1]); a[2] = f2bf(e0[2]); a[3] = f2bf(e0[3]);
      a[4] = f2bf(e1[0]); a[5] = f2bf(e1[1]); a[6] = f2bf(e1[2]); a[7] = f2bf(e1[3]);
      const f32x4 c0 = __builtin_amdgcn_mfma_f32_16x16x32_bf16(bfr[n][0], a, z, 0, 0, 0);
      const f32x4 c1 = __builtin_amdgcn_mfma_f32_16x16x32_bf16(bfr[n][1], a, z, 0, 0, 0);
      float* op = outb + (size_t)(m0 + lr) * (NN * HH) + n * HH + lk * 4;
      *(f32x4*)op        = c0;
      *(f32x4*)(op + 16) = c1;
    }
  }
}

extern "C" void kernel_launch(void* const* d_in, const int* in_sizes, int n_in,
                              void* d_out, int out_size, void* d_ws, size_t ws_size,
                              hipStream_t stream) {
  const float* d = (const float*)d_in[0];
  const float* e = (const float*)d_in[1];
  const float* W = (const float*)d_in[2];
  float* out = (float*)d_out;

  const size_t tmp_bytes = (size_t)BB * PP * NN * HH * HH * sizeof(short); // 16.78 MB
  const size_t eb_bytes  = (size_t)BB * PP * NN * HH * sizeof(short);      // 512 KB
  if (ws_size >= tmp_bytes + eb_bytes) {
    short* tmpT = (short*)d_ws;
    short* eBf  = (short*)((char*)d_ws + tmp_bytes);
    prep_all_kernel<<<dim3(512 + 128), dim3(256), 0, stream>>>(d, W, e, tmpT, eBf);
    vmain_kernel<<<dim3(BB * PP), dim3(256), 0, stream>>>(eBf, tmpT, out);
  } else {
    fused_kernel<<<dim3(BB * PP), dim3(256), 0, stream>>>(d, e, W, out);
  }
}

// Round 11
// 125.332 us; speedup vs baseline: 1.1123x; 1.0127x over previous
//
#include <hip/hip_runtime.h>

// dims from the reference
#define BB 2
#define PP 512
#define NN 8
#define HH 32

typedef float f4     __attribute__((ext_vector_type(4)));
typedef float f32x4  __attribute__((ext_vector_type(4)));
typedef short bf16x8 __attribute__((ext_vector_type(8)));

// float -> bf16 bits, round-nearest-even
__device__ __forceinline__ short f2bf(float f) {
  union { float f; unsigned u; } v; v.f = f;
  unsigned r = v.u + 0x7FFFu + ((v.u >> 16) & 1u);
  return (short)(r >> 16);
}

// ---------------------------------------------------------------------------
// Kernel 1: prep_all (unchanged from R8/R10)
//  blocks 0..511  : tmpT[b,p1,n,h3,h2] = bf16( sum_h1 d * W ), W read direct.
//  blocks 512..639: eBf tiled bf16 fragment layout (1KB dense B-frag loads).
// ---------------------------------------------------------------------------
__global__ __launch_bounds__(256) void prep_all_kernel(
    const float* __restrict__ d, const float* __restrict__ W,
    const float* __restrict__ e, short* __restrict__ tmpT,
    short* __restrict__ eBf) {
  const int bid = blockIdx.x;
  const int t   = threadIdx.x;

  if (bid >= 512) {                    // ---- eBf tiled conversion ----
    const int ft = (bid - 512) * 256 + t;      // 0..32767
    const int l  = ft & 63;
    const int n  = (ft >> 6) & 7;
    const int pt = (ft >> 9) & 31;
    const int b  = ft >> 14;
    const float* src =
        e + (((size_t)(b * PP + pt * 16 + (l & 15)) * NN + n) * HH + (l >> 4) * 8);
    const f4 e0 = *(const f4*)src;
    const f4 e1 = *(const f4*)(src + 4);
    bf16x8 v;
    v[0] = f2bf(e0[0]); v[1] = f2bf(e0[1]); v[2] = f2bf(e0[2]); v[3] = f2bf(e0[3]);
    v[4] = f2bf(e1[0]); v[5] = f2bf(e1[1]); v[6] = f2bf(e1[2]); v[7] = f2bf(e1[3]);
    *(bf16x8*)(eBf + (size_t)ft * 8) = v;
    return;
  }

  // ---- prep part: block = (b, n-pair, 8 p1) ----
  const int b      = bid >> 8;
  const int rem    = bid & 255;
  const int npair  = rem >> 6;         // 0..3
  const int p1base = (rem & 63) * 8;

  __shared__ float dsh[2][32][8];      // [n'][h1][p1l]
  {
    const int h1 = t & 31, p1l = (t >> 5) & 7;
    #pragma unroll
    for (int r = 0; r < 2; ++r)
      dsh[r][h1][p1l] =
          d[(size_t)((b * PP + p1base + p1l) * NN + npair * 2 + r) * HH + h1];
  }
  __syncthreads();

  const int np  = t >> 7;              // 0/1
  const int h3  = (t >> 2) & 31;
  const int h2g = t & 3;               // h2 base = h2g*8
  const int n   = npair * 2 + np;

  float acc[8][8];                     // [p1l][h2loc]
  #pragma unroll
  for (int p = 0; p < 8; ++p)
    #pragma unroll
    for (int q = 0; q < 8; ++q) acc[p][q] = 0.f;

  const float* wb = W + (size_t)n * 32768 + h2g * 8 * 32 + h3;
  for (int h1 = 0; h1 < 32; ++h1) {
    const float* wr = wb + (size_t)h1 * 1024;
    float wq[8];
    #pragma unroll
    for (int q = 0; q < 8; ++q) wq[q] = wr[q * 32];
    const f4 d0 = *(const f4*)&dsh[np][h1][0];
    const f4 d1 = *(const f4*)&dsh[np][h1][4];
    #pragma unroll
    for (int p = 0; p < 4; ++p) {
      #pragma unroll
      for (int q = 0; q < 4; ++q) {
        acc[p][q]         = fmaf(d0[p], wq[q],     acc[p][q]);
        acc[p][q + 4]     = fmaf(d0[p], wq[q + 4], acc[p][q + 4]);
        acc[p + 4][q]     = fmaf(d1[p], wq[q],     acc[p + 4][q]);
        acc[p + 4][q + 4] = fmaf(d1[p], wq[q + 4], acc[p + 4][q + 4]);
      }
    }
  }

  const size_t obase =
      ((size_t)(b * PP + p1base) * NN + n) * (HH * HH) + h3 * 32 + h2g * 8;
  #pragma unroll
  for (int p = 0; p < 8; ++p) {
    bf16x8 v;
    #pragma unroll
    for (int q = 0; q < 8; ++q) v[q] = f2bf(acc[p][q]);
    *(bf16x8*)(tmpT + obase + (size_t)p * (NN * HH * HH)) = v;
  }
}

// ---------------------------------------------------------------------------
// Kernel 2: vmain v11 — R10 cooperative epilogue, 2 TILES PER BARRIER.
//   sh = [2][32][256] f32 (64 KB, double-buffered 32-row windows).
//   Per iter (16 total): each wave computes its 2 n for tiles 2i and 2i+1
//   (8 MFMA), one barrier, then stores 8 CONSECUTIVE full 1KB rows
//   (wave wv owns rows wv*8..wv*8+7 of the 32-row window) — 8KB monotonic
//   burst per wave, 32KB per block window. 2 blocks/CU (fill evidence:
//   ~3.5 waves/CU suffice for write BW).
// ---------------------------------------------------------------------------
__global__ __launch_bounds__(256, 2) void vmain_kernel(
    const short* __restrict__ eBf, const short* __restrict__ tmpT,
    float* __restrict__ out) {
  const int bid = blockIdx.x;
  const int b   = bid >> 9;
  const int p1  = bid & 511;
  const int t   = threadIdx.x;
  const int wv  = t >> 6;
  const int l   = t & 63;
  const int lr  = l & 15;
  const int lk  = l >> 4;
  const int n0w = wv * 2;              // this wave's n pair

  __shared__ float sh[2][32][256];     // 64 KB: double-buffered 32-row windows

  // A-fragments for this wave's two n: rows h3 = c*16+lr, k = h2 = 8*lk+j
  bf16x8 bfr[2][2];
  const short* tb = tmpT + (size_t)(b * PP + p1) * (NN * HH * HH);
  #pragma unroll
  for (int s = 0; s < 2; ++s)
    #pragma unroll
    for (int c = 0; c < 2; ++c)
      bfr[s][c] =
          *(const bf16x8*)(tb + (n0w + s) * 1024 + (c * 16 + lr) * 32 + lk * 8);

  const short* eb   = eBf + (size_t)b * (32 * NN * 512);
  float*       outb = out + (size_t)(b * PP + p1) * (PP * NN * HH);
  const f32x4  z    = {0.f, 0.f, 0.f, 0.f};

  for (int i = 0; i < 16; ++i) {       // 2 tiles (32 p2 rows) per iteration
    const int bi = i & 1;
    // ---- compute: tiles 2i, 2i+1; this wave's 64 cols of each ----
    #pragma unroll
    for (int tt = 0; tt < 2; ++tt) {
      const int pt = 2 * i + tt;
      #pragma unroll
      for (int s = 0; s < 2; ++s) {
        const int n = n0w + s;
        const bf16x8 a =
            *(const bf16x8*)(eb + (((size_t)(pt * NN + n)) << 9) + l * 8);
        const f32x4 c0 = __builtin_amdgcn_mfma_f32_16x16x32_bf16(bfr[s][0], a, z, 0, 0, 0);
        const f32x4 c1 = __builtin_amdgcn_mfma_f32_16x16x32_bf16(bfr[s][1], a, z, 0, 0, 0);
        // lane: p2-row = lr (local), h3 groups lk / 4+lk of col-block n
        const int g0 = (n * 8 + lk)     ^ (lr & 7);   // 16B-group swizzle
        const int g1 = (n * 8 + 4 + lk) ^ (lr & 7);
        *(f32x4*)(&sh[bi][tt * 16 + lr][g0 * 4]) = c0;
        *(f32x4*)(&sh[bi][tt * 16 + lr][g1 * 4]) = c1;
      }
    }
    __syncthreads();                   // window ready (dbuf: 1 barrier/iter)
    // ---- store: 8 consecutive full 1KB rows per wave ----
    #pragma unroll
    for (int k = 0; k < 8; ++k) {
      const int r = wv * 8 + k;        // 0..31 within window
      const f32x4 v = *(const f32x4*)(&sh[bi][r][((l ^ (r & 7)) * 4)]);
      *(f32x4*)(outb + (size_t)(i * 32 + r) * 256 + l * 4) = v;
    }
  }
}

// ---------------------------------------------------------------------------
// Fallback (no/small ws): self-contained fused kernel (correct, slower).
// ---------------------------------------------------------------------------
__global__ __launch_bounds__(256, 4) void fused_kernel(
    const float* __restrict__ d, const float* __restrict__ e,
    const float* __restrict__ W, float* __restrict__ out) {
  const int bid = blockIdx.x;
  const int b   = bid >> 9;
  const int p1  = bid & 511;
  const int t   = threadIdx.x;

  __shared__ float dsh[NN * HH];
  __shared__ short tsh[NN * HH * HH];
  dsh[t] = d[(size_t)(b * PP + p1) * (NN * HH) + t];
  __syncthreads();

  const int h3  = t & 31;
  const int h2b = t >> 5;
  for (int n = 0; n < 8; ++n) {
    f4 dv[8];
    #pragma unroll
    for (int j = 0; j < 8; ++j) dv[j] = *(const f4*)&dsh[n * 32 + j * 4];
    const float* Wn = W + (size_t)n * (HH * HH * HH);
    #pragma unroll
    for (int h2s = 0; h2s < 4; ++h2s) {
      const int h2 = h2s * 8 + h2b;
      float acc = 0.f;
      #pragma unroll
      for (int j = 0; j < 8; ++j)
        #pragma unroll
        for (int k = 0; k < 4; ++k)
          acc = fmaf(dv[j][k], Wn[(j * 4 + k) * 1024 + h2 * 32 + h3], acc);
      tsh[n * 1024 + h3 * 32 + h2] = f2bf(acc);
    }
  }
  __syncthreads();

  const int wv = t >> 6;
  const int l  = t & 63;
  const int lr = l & 15;
  const int lk = l >> 4;
  bf16x8 bfr[8][2];
  #pragma unroll
  for (int n = 0; n < 8; ++n)
    #pragma unroll
    for (int c = 0; c < 2; ++c)
      bfr[n][c] = *(const bf16x8*)&tsh[n * (HH * HH) + (c * 16 + lr) * 32 + lk * 8];

  const float* eb   = e + (size_t)b * (PP * NN * HH);
  float*       outb = out + (size_t)(b * PP + p1) * (PP * NN * HH);
  const f32x4  z    = {0.f, 0.f, 0.f, 0.f};
  for (int i = 0; i < 8; ++i) {
    const int m0 = (wv * 8 + i) * 16;
    #pragma unroll
    for (int n = 0; n < 8; ++n) {
      const float* ep = eb + (size_t)(((m0 + lr) * NN + n) * HH + lk * 8);
      const f4 e0 = *(const f4*)ep;
      const f4 e1 = *(const f4*)(ep + 4);
      bf16x8 a;
      a[0] = f2bf(e0[0]); a[1] = f2bf(e0[1]); a[2] = f2bf(e0[2]); a[3] = f2bf(e0[3]);
      a[4] = f2bf(e1[0]); a[5] = f2bf(e1[1]); a[6] = f2bf(e1[2]); a[7] = f2bf(e1[3]);
      const f32x4 c0 = __builtin_amdgcn_mfma_f32_16x16x32_bf16(bfr[n][0], a, z, 0, 0, 0);
      const f32x4 c1 = __builtin_amdgcn_mfma_f32_16x16x32_bf16(bfr[n][1], a, z, 0, 0, 0);
      float* op = outb + (size_t)(m0 + lr) * (NN * HH) + n * HH + lk * 4;
      *(f32x4*)op        = c0;
      *(f32x4*)(op + 16) = c1;
    }
  }
}

extern "C" void kernel_launch(void* const* d_in, const int* in_sizes, int n_in,
                              void* d_out, int out_size, void* d_ws, size_t ws_size,
                              hipStream_t stream) {
  const float* d = (const float*)d_in[0];
  const float* e = (const float*)d_in[1];
  const float* W = (const float*)d_in[2];
  float* out = (float*)d_out;

  const size_t tmp_bytes = (size_t)BB * PP * NN * HH * HH * sizeof(short); // 16.78 MB
  const size_t eb_bytes  = (size_t)BB * PP * NN * HH * sizeof(short);      // 512 KB
  if (ws_size >= tmp_bytes + eb_bytes) {
    short* tmpT = (short*)d_ws;
    short* eBf  = (short*)((char*)d_ws + tmp_bytes);
    prep_all_kernel<<<dim3(512 + 128), dim3(256), 0, stream>>>(d, W, e, tmpT, eBf);
    vmain_kernel<<<dim3(BB * PP), dim3(256), 0, stream>>>(eBf, tmpT, out);
  } else {
    fused_kernel<<<dim3(BB * PP), dim3(256), 0, stream>>>(d, e, W, out);
  }
}